// Round 1
// baseline (2558.740 us; speedup 1.0000x reference)
//
#include <hip/hip_runtime.h>
#include <hip/hip_bf16.h>
#include <cmath>

#define EB 32           // edges per block (edge kernel)
#define EDGE_THREADS 512
#define NB 32           // nodes per block (node kernel)
#define NODE_THREADS 256

// ---------------------------------------------------------------------------
// Edge kernel: for one conv (l,t): per edge
//   rbf = cutoff(d) * exp(-beta*(exp(-d)-means)^2)           (128 features)
//   ss  = rbf @ Wd + bd   -> scale (0:128), shift (128:256)
//   xj  = x_src[src] + ea @ (W0t @ We) + be
//   msg = relu(xj*scale + shift);  atomicAdd into agg[dst]
// Block: 512 threads, 32 edges. GEMM: 32x256 C-tile, 4x4 per-thread tiles.
// ---------------------------------------------------------------------------
__global__ __launch_bounds__(EDGE_THREADS)
void edge_msg_kernel(const float* __restrict__ x_src,
                     const int* __restrict__ ei,     // (2,E)
                     const float* __restrict__ ew,   // (E)
                     const float* __restrict__ ea,   // (E,4)
                     const float* __restrict__ Wd,   // (128,256) for (l,t)
                     const float* __restrict__ bd,   // (256)
                     const float* __restrict__ W0t,  // (4,4) for t
                     const float* __restrict__ We,   // (4,128) for (l,t)
                     const float* __restrict__ be,   // (128)
                     float* __restrict__ agg,        // (N,128)
                     int E,
                     float rbf_start, float rbf_step, float rbf_beta)
{
    __shared__ float sWd[32 * 256];   // k-chunk of Wd; reused for ss after GEMM
    __shared__ float sRbf[32 * EB];   // [kk][e]
    __shared__ float sEd[EB], sCut[EB];
    __shared__ int   sSrc[EB], sDst[EB];
    __shared__ float sEA[EB * 4];
    __shared__ float sM[4 * 128];     // (W0t @ We)[a][h]

    const int t  = threadIdx.x;
    const int e0 = blockIdx.x * EB;

    // ---- prologue: per-edge scalars ----
    if (t < EB) {
        int eg = e0 + t;
        int ec = eg < E ? eg : E - 1;
        float d  = ew[ec];
        sEd[t]   = expf(-d);
        float dc = fminf(d, 5.0f);
        sCut[t]  = 0.5f * (cosf(dc * 0.62831853071795864769f) + 1.0f); // pi/5
        sSrc[t]  = ei[ec];
        sDst[t]  = ei[E + ec];
    }
    if (t < EB * 4) {
        int eg = e0 + (t >> 2);
        int ec = eg < E ? eg : E - 1;
        sEA[t] = ea[(size_t)ec * 4 + (t & 3)];
    }
    {   // sM[a][h] = sum_j W0t[a][j] * We[j][h]
        int h = t & 127;
        int a = t >> 7;          // 0..3 with 512 threads
        float m = 0.f;
        #pragma unroll
        for (int j = 0; j < 4; ++j) m = fmaf(W0t[a * 4 + j], We[j * 128 + h], m);
        sM[a * 128 + h] = m;
    }

    float acc[16];
    #pragma unroll
    for (int i = 0; i < 16; ++i) acc[i] = 0.f;

    const int cg  = t & 63;       // column group -> cols 4*cg..+3 (of 256)
    const int eg4 = t >> 6;       // edge group   -> edges 4*eg4..+3 (of 32)
    const int c0  = cg * 4;
    const int le0 = eg4 * 4;

    // ---- GEMM: ss(32x256) = rbf(32x128) @ Wd(128x256), k-chunks of 32 ----
    for (int k0 = 0; k0 < 128; k0 += 32) {
        __syncthreads();
        {   // stage Wd chunk (contiguous 8192 floats)
            const float4* src = (const float4*)(Wd + (size_t)k0 * 256);
            float4* dst = (float4*)sWd;
            #pragma unroll
            for (int i = 0; i < 4; ++i) dst[i * 512 + t] = src[i * 512 + t];
        }
        {   // fill rbf [kk][e]: 1024 values, 2 per thread
            int idx = t * 2;
            int kk  = idx >> 5;
            int e   = idx & 31;
            float mean = rbf_start + (float)(k0 + kk) * rbf_step;
            #pragma unroll
            for (int u = 0; u < 2; ++u) {
                float diff = sEd[e + u] - mean;
                sRbf[kk * EB + e + u] = sCut[e + u] * expf(-rbf_beta * diff * diff);
            }
        }
        __syncthreads();
        #pragma unroll
        for (int kk = 0; kk < 32; ++kk) {
            float4 rb = *(const float4*)&sRbf[kk * EB + le0];
            float4 w  = *(const float4*)&sWd[kk * 256 + c0];
            float rbv[4] = {rb.x, rb.y, rb.z, rb.w};
            float wv[4]  = {w.x, w.y, w.z, w.w};
            #pragma unroll
            for (int j = 0; j < 4; ++j)
                #pragma unroll
                for (int m = 0; m < 4; ++m)
                    acc[j * 4 + m] = fmaf(rbv[j], wv[m], acc[j * 4 + m]);
        }
    }

    // ---- ss = acc + bd -> LDS (reuse sWd) ----
    __syncthreads();
    {
        float4 bd4 = *(const float4*)&bd[c0];
        float4* sSS4 = (float4*)sWd;
        #pragma unroll
        for (int j = 0; j < 4; ++j) {
            float4 v;
            v.x = acc[j * 4 + 0] + bd4.x;
            v.y = acc[j * 4 + 1] + bd4.y;
            v.z = acc[j * 4 + 2] + bd4.z;
            v.w = acc[j * 4 + 3] + bd4.w;
            sSS4[(le0 + j) * 64 + cg] = v;
        }
    }
    __syncthreads();

    // ---- epilogue: msg + scatter. 32 edges x 128 h = 4096 / 512 thr = 8 ----
    {
        const int h = t & 127;
        const int g = t >> 7;     // 0..3
        float beh = be[h];
        float m0 = sM[0 * 128 + h], m1 = sM[1 * 128 + h];
        float m2 = sM[2 * 128 + h], m3 = sM[3 * 128 + h];
        #pragma unroll
        for (int i = 0; i < 8; ++i) {
            int e = g + 4 * i;
            if (e0 + e < E) {
                float scale = sWd[e * 256 + h];
                float shift = sWd[e * 256 + 128 + h];
                float eam = sEA[e * 4 + 0] * m0 + sEA[e * 4 + 1] * m1 +
                            sEA[e * 4 + 2] * m2 + sEA[e * 4 + 3] * m3;
                float xj  = x_src[(size_t)sSrc[e] * 128 + h] + eam + beh;
                float msg = fmaxf(fmaf(xj, scale, shift), 0.f);
                atomicAdd(&agg[(size_t)sDst[e] * 128 + h], msg);
            }
        }
    }
}

// ---------------------------------------------------------------------------
// Node kernel: out = relu((agg + x_dst) @ W1 + b1) @ W2 + b2
// optional accumulate into out (lig = sum of two convs), optional final relu.
// Block: 256 threads, 32-node tile; 4x4 per-thread subtiles; W from global(L1/L2).
// ---------------------------------------------------------------------------
__global__ __launch_bounds__(NODE_THREADS)
void node_mlp_kernel(const float* __restrict__ agg,
                     const float* __restrict__ x_dst,
                     const float* __restrict__ W1, const float* __restrict__ b1,
                     const float* __restrict__ W2, const float* __restrict__ b2,
                     float* __restrict__ out,
                     int N, int accumulate, int relu_out)
{
    __shared__ float sA[NB * 128];   // o = agg + x_dst, [n][k]
    __shared__ float sH[NB * 128];   // hidden,          [n][k]

    const int t  = threadIdx.x;
    const int n0 = blockIdx.x * NB;

    {   // stage o = agg + x_dst (tile is contiguous rows n0..n0+31)
        const float4* a4 = (const float4*)agg;
        const float4* x4 = (const float4*)x_dst;
        float4* s4 = (float4*)sA;
        size_t base = (size_t)n0 * 32;   // float4 units
        #pragma unroll
        for (int i = 0; i < 4; ++i) {
            int idx = i * 256 + t;       // 0..1023
            float4 a = a4[base + idx];
            float4 x = x4[base + idx];
            float4 o; o.x = a.x + x.x; o.y = a.y + x.y; o.z = a.z + x.z; o.w = a.w + x.w;
            s4[idx] = o;
        }
    }
    __syncthreads();

    const int cg  = t & 31;       // cols 4*cg..+3 (of 128)
    const int ng  = t >> 5;       // nodes 4*ng..+3 (of 32)
    const int c0  = cg * 4;
    const int ln0 = ng * 4;

    float acc[16];
    #pragma unroll
    for (int i = 0; i < 16; ++i) acc[i] = 0.f;

    // stage A: hidden = relu(o @ W1 + b1)
    for (int k = 0; k < 128; ++k) {
        float4 w = *(const float4*)&W1[(size_t)k * 128 + c0];
        float a0 = sA[(ln0 + 0) * 128 + k];
        float a1 = sA[(ln0 + 1) * 128 + k];
        float a2 = sA[(ln0 + 2) * 128 + k];
        float a3 = sA[(ln0 + 3) * 128 + k];
        acc[0]  = fmaf(a0, w.x, acc[0]);  acc[1]  = fmaf(a0, w.y, acc[1]);
        acc[2]  = fmaf(a0, w.z, acc[2]);  acc[3]  = fmaf(a0, w.w, acc[3]);
        acc[4]  = fmaf(a1, w.x, acc[4]);  acc[5]  = fmaf(a1, w.y, acc[5]);
        acc[6]  = fmaf(a1, w.z, acc[6]);  acc[7]  = fmaf(a1, w.w, acc[7]);
        acc[8]  = fmaf(a2, w.x, acc[8]);  acc[9]  = fmaf(a2, w.y, acc[9]);
        acc[10] = fmaf(a2, w.z, acc[10]); acc[11] = fmaf(a2, w.w, acc[11]);
        acc[12] = fmaf(a3, w.x, acc[12]); acc[13] = fmaf(a3, w.y, acc[13]);
        acc[14] = fmaf(a3, w.z, acc[14]); acc[15] = fmaf(a3, w.w, acc[15]);
    }
    {
        float4 b1v = *(const float4*)&b1[c0];
        float4* s4 = (float4*)sH;
        #pragma unroll
        for (int j = 0; j < 4; ++j) {
            float4 v;
            v.x = fmaxf(acc[j * 4 + 0] + b1v.x, 0.f);
            v.y = fmaxf(acc[j * 4 + 1] + b1v.y, 0.f);
            v.z = fmaxf(acc[j * 4 + 2] + b1v.z, 0.f);
            v.w = fmaxf(acc[j * 4 + 3] + b1v.w, 0.f);
            s4[(ln0 + j) * 32 + cg] = v;
        }
    }
    __syncthreads();

    #pragma unroll
    for (int i = 0; i < 16; ++i) acc[i] = 0.f;

    // stage B: out = hidden @ W2 + b2
    for (int k = 0; k < 128; ++k) {
        float4 w = *(const float4*)&W2[(size_t)k * 128 + c0];
        float a0 = sH[(ln0 + 0) * 128 + k];
        float a1 = sH[(ln0 + 1) * 128 + k];
        float a2 = sH[(ln0 + 2) * 128 + k];
        float a3 = sH[(ln0 + 3) * 128 + k];
        acc[0]  = fmaf(a0, w.x, acc[0]);  acc[1]  = fmaf(a0, w.y, acc[1]);
        acc[2]  = fmaf(a0, w.z, acc[2]);  acc[3]  = fmaf(a0, w.w, acc[3]);
        acc[4]  = fmaf(a1, w.x, acc[4]);  acc[5]  = fmaf(a1, w.y, acc[5]);
        acc[6]  = fmaf(a1, w.z, acc[6]);  acc[7]  = fmaf(a1, w.w, acc[7]);
        acc[8]  = fmaf(a2, w.x, acc[8]);  acc[9]  = fmaf(a2, w.y, acc[9]);
        acc[10] = fmaf(a2, w.z, acc[10]); acc[11] = fmaf(a2, w.w, acc[11]);
        acc[12] = fmaf(a3, w.x, acc[12]); acc[13] = fmaf(a3, w.y, acc[13]);
        acc[14] = fmaf(a3, w.z, acc[14]); acc[15] = fmaf(a3, w.w, acc[15]);
    }
    {
        float4 b2v = *(const float4*)&b2[c0];
        #pragma unroll
        for (int j = 0; j < 4; ++j) {
            int row = n0 + ln0 + j;
            if (row < N) {
                float4 v;
                v.x = acc[j * 4 + 0] + b2v.x;
                v.y = acc[j * 4 + 1] + b2v.y;
                v.z = acc[j * 4 + 2] + b2v.z;
                v.w = acc[j * 4 + 3] + b2v.w;
                float4* op = (float4*)&out[(size_t)row * 128 + c0];
                if (accumulate) {
                    float4 p = *op;
                    v.x += p.x; v.y += p.y; v.z += p.z; v.w += p.w;
                }
                if (relu_out) {
                    v.x = fmaxf(v.x, 0.f); v.y = fmaxf(v.y, 0.f);
                    v.z = fmaxf(v.z, 0.f); v.w = fmaxf(v.w, 0.f);
                }
                *op = v;
            }
        }
    }
}

// ---------------------------------------------------------------------------
extern "C" void kernel_launch(void* const* d_in, const int* in_sizes, int n_in,
                              void* d_out, int out_size, void* d_ws, size_t ws_size,
                              hipStream_t stream)
{
    const float* x_lig   = (const float*)d_in[0];
    const float* x_pock  = (const float*)d_in[1];
    const int*   ei_bond = (const int*)d_in[2];
    const float* ew_bond = (const float*)d_in[3];
    const float* ea_bond = (const float*)d_in[4];
    const int*   ei_lp   = (const int*)d_in[5];
    const float* ew_lp   = (const float*)d_in[6];
    const float* ea_lp   = (const float*)d_in[7];
    const int*   ei_pl   = (const int*)d_in[8];
    const float* ew_pl   = (const float*)d_in[9];
    const float* ea_pl   = (const float*)d_in[10];
    const float* W0 = (const float*)d_in[11];
    const float* Wd = (const float*)d_in[12];
    const float* bd = (const float*)d_in[13];
    const float* We = (const float*)d_in[14];
    const float* be = (const float*)d_in[15];
    const float* W1 = (const float*)d_in[16];
    const float* b1 = (const float*)d_in[17];
    const float* W2 = (const float*)d_in[18];
    const float* b2 = (const float*)d_in[19];

    const int H = 128;
    const int N = in_sizes[0] / H;
    const int E_bond = in_sizes[3];
    const int E_lp   = in_sizes[6];
    const int E_pl   = in_sizes[9];

    float* agg   = (float*)d_ws;                  // N*128
    float* lig0  = agg  + (size_t)N * H;          // layer-0 lig out
    float* pock0 = lig0 + (size_t)N * H;          // layer-0 pock out
    float* outL  = (float*)d_out;                 // layer-1 lig out
    float* outP  = outL + (size_t)N * H;          // layer-1 pock out

    const double start_d = exp(-5.0);
    const float rs    = (float)start_d;
    const float rstep = (float)((1.0 - start_d) / 127.0);
    const float rbeta = (float)std::pow(2.0 / 128.0 * (1.0 - start_d), -2.0);

    auto conv = [&](const float* xsrc, const float* xdst, const int* ei,
                    const float* ew, const float* ea, int E, int l, int tt,
                    float* outbuf, int accum, int relu) {
        hipMemsetAsync(agg, 0, (size_t)N * H * sizeof(float), stream);
        const size_t lt = (size_t)(l * 3 + tt);
        edge_msg_kernel<<<(E + EB - 1) / EB, EDGE_THREADS, 0, stream>>>(
            xsrc, ei, ew, ea,
            Wd + lt * 128 * 256, bd + lt * 256,
            W0 + (size_t)tt * 16, We + lt * 4 * 128, be + lt * 128,
            agg, E, rs, rstep, rbeta);
        node_mlp_kernel<<<(N + NB - 1) / NB, NODE_THREADS, 0, stream>>>(
            agg, xdst,
            W1 + lt * 128 * 128, b1 + lt * 128,
            W2 + lt * 128 * 128, b2 + lt * 128,
            outbuf, N, accum, relu);
    };

    for (int l = 0; l < 2; ++l) {
        const float* xl = l ? lig0  : x_lig;
        const float* xp = l ? pock0 : x_pock;
        float* nl  = l ? outL : lig0;
        float* np_ = l ? outP : pock0;
        int relu = (l == 0);
        // new_pock = conv(x_lig -> x_pock, lp, t=1)
        conv(xl, xp, ei_lp, ew_lp, ea_lp, E_lp, l, 1, np_, 0, relu);
        // new_lig  = conv(x_lig -> x_lig, bond, t=0) ...
        conv(xl, xl, ei_bond, ew_bond, ea_bond, E_bond, l, 0, nl, 0, 0);
        //          ... + conv(x_pock -> x_lig, pl, t=2), relu after sum
        conv(xp, xl, ei_pl, ew_pl, ea_pl, E_pl, l, 2, nl, 1, relu);
    }
}

// Round 2
// 2289.855 us; speedup vs baseline: 1.1174x; 1.1174x over previous
//
#include <hip/hip_runtime.h>
#include <hip/hip_bf16.h>
#include <cmath>

typedef __attribute__((ext_vector_type(8))) short short8;
typedef __attribute__((ext_vector_type(4))) float f32x4;

static __device__ __forceinline__ short f2bs(float f) {
    union { __hip_bfloat16 h; short s; } u;
    u.h = __float2bfloat16(f);
    return u.s;
}

// ---------------------------------------------------------------------------
// Pack kernel: Wd/W1/W2 -> bf16 MFMA B-fragment order; M = W0t @ We (fp32).
// B-frag layout: p[((kk*NT+nt)*64 + lane)*8 + j] = W[kk*32+(lane>>4)*8+j][nt*16+(lane&15)]
// ---------------------------------------------------------------------------
__global__ void pack_kernel(const float* __restrict__ Wd,
                            const float* __restrict__ W1,
                            const float* __restrict__ W2,
                            const float* __restrict__ W0,
                            const float* __restrict__ We,
                            short* __restrict__ pWd,
                            short* __restrict__ pW1,
                            short* __restrict__ pW2,
                            float* __restrict__ Mb)
{
    const int tid = blockIdx.x * blockDim.x + threadIdx.x;
    const int stride = gridDim.x * blockDim.x;
    // Wd: 6 convs x (KK=4, NT=16)
    for (int i = tid; i < 6 * 32768; i += stride) {
        int c = i >> 15, rem = i & 32767;
        int f = rem >> 9, l = (rem >> 3) & 63, j = rem & 7;
        int kk = f >> 4, nt = f & 15;
        int k = kk * 32 + (l >> 4) * 8 + j;
        int n = nt * 16 + (l & 15);
        pWd[i] = f2bs(Wd[(size_t)c * 32768 + k * 256 + n]);
    }
    // W1/W2: 6 convs x (KK=4, NT=8)
    for (int i = tid; i < 6 * 16384; i += stride) {
        int c = i >> 14, rem = i & 16383;
        int f = rem >> 9, l = (rem >> 3) & 63, j = rem & 7;
        int kk = f >> 3, nt = f & 7;
        int k = kk * 32 + (l >> 4) * 8 + j;
        int n = nt * 16 + (l & 15);
        pW1[i] = f2bs(W1[(size_t)c * 16384 + k * 128 + n]);
        pW2[i] = f2bs(W2[(size_t)c * 16384 + k * 128 + n]);
    }
    // M[c][a][h] = sum_j W0[t][a][j] * We[c][j][h],  t = c % 3
    for (int i = tid; i < 6 * 512; i += stride) {
        int c = i >> 9, rem = i & 511;
        int a = rem >> 7, h = rem & 127;
        int t = c % 3;
        float m = 0.f;
        #pragma unroll
        for (int j = 0; j < 4; ++j)
            m = fmaf(W0[t * 16 + a * 4 + j], We[(size_t)c * 512 + j * 128 + h], m);
        Mb[i] = m;
    }
}

// ---------------------------------------------------------------------------
// Edge kernel (persistent): 64 edges/tile, 256 threads (4 waves).
// Wave w owns output cols [32w,32w+32) of scale AND shift (nt = 2w,2w+1,8+2w,9+2w)
// so the epilogue is wave-local. B frags (Wd) held in registers across tiles.
// ---------------------------------------------------------------------------
__global__ void edge_mfma_kernel(
    const float* __restrict__ x_src, const int* __restrict__ ei,
    const float* __restrict__ ew, const float* __restrict__ ea,
    const short* __restrict__ pWd, const float* __restrict__ bd,
    const float* __restrict__ Mb, const float* __restrict__ be,
    float* __restrict__ agg, int E, int ntiles,
    float rs, float rstep, float rbeta)
{
    __shared__ short sRbf[64 * 128];   // bf16, XOR-swizzled, 16 KB
    __shared__ float sXj[64 * 130];    // fp32, padded stride 130, 33.3 KB
    __shared__ float sEd[64], sCut[64];
    __shared__ int   sSrc[64], sDst[64];
    __shared__ float sEA[64 * 4];

    const int t = threadIdx.x;
    const int lane = t & 63;
    const int w = t >> 6;
    const int l15 = lane & 15;
    const int l4 = lane >> 4;

    // --- per-block constants ---
    short8 bfrag[4][4];   // [kk][0,1: scale p / 2,3: shift p]
    #pragma unroll
    for (int kk = 0; kk < 4; ++kk)
        #pragma unroll
        for (int i = 0; i < 4; ++i) {
            int nt = (i < 2) ? (2 * w + i) : (8 + 2 * w + (i - 2));
            bfrag[kk][i] = *(const short8*)&pWd[((kk * 16 + nt) * 64 + lane) * 8];
        }
    float bdS[2], bdH[2];
    #pragma unroll
    for (int p = 0; p < 2; ++p) {
        int h = (2 * w + p) * 16 + l15;
        bdS[p] = bd[h];
        bdH[p] = bd[128 + h];
    }
    const float be0 = be[2 * lane], be1 = be[2 * lane + 1];
    float ma0[4], ma1[4];
    #pragma unroll
    for (int a = 0; a < 4; ++a) {
        ma0[a] = Mb[a * 128 + 2 * lane];
        ma1[a] = Mb[a * 128 + 2 * lane + 1];
    }

    for (int tile = blockIdx.x; tile < ntiles; tile += gridDim.x) {
        const int e0 = tile << 6;
        __syncthreads();   // protect per-edge LDS vs previous iteration's reads
        if (w == 0) {
            int eg = e0 + lane;
            int ec = eg < E ? eg : E - 1;
            float d = ew[ec];
            sEd[lane] = __expf(-d);
            float dc = fminf(d, 5.0f);
            sCut[lane] = 0.5f * (__cosf(dc * 0.62831853071795864769f) + 1.0f);
            sSrc[lane] = ei[ec];
            sDst[lane] = (eg < E) ? ei[E + ec] : -1;
        } else if (w == 1) {
            int eg = e0 + lane;
            int ec = eg < E ? eg : E - 1;
            float4 v = *(const float4*)&ea[(size_t)ec * 4];
            *(float4*)&sEA[lane * 4] = v;
        }
        __syncthreads();

        // --- rbf -> LDS bf16 (wave w covers k in [32w, 32w+32), edge = lane) ---
        {
            const float ed = sEd[lane], cut = sCut[lane];
            char* base = (char*)sRbf + lane * 256;
            #pragma unroll
            for (int c = 0; c < 4; ++c) {
                short8 v;
                #pragma unroll
                for (int j = 0; j < 8; ++j) {
                    float mean = rs + (float)(w * 32 + c * 8 + j) * rstep;
                    float diff = ed - mean;
                    v[j] = f2bs(cut * __expf(-rbeta * diff * diff));
                }
                *(short8*)(base + ((w * 64 + c * 16) ^ ((lane & 7) << 4))) = v;
            }
        }

        // --- xj staging: wave w stages rows [16w, 16w+16) ---
        #pragma unroll
        for (int r = 0; r < 16; ++r) {
            int e = w * 16 + r;
            int srcn = sSrc[e];
            float2 xv = *(const float2*)&x_src[(size_t)srcn * 128 + lane * 2];
            float ea0 = sEA[e * 4 + 0], ea1 = sEA[e * 4 + 1];
            float ea2 = sEA[e * 4 + 2], ea3 = sEA[e * 4 + 3];
            float2 o;
            o.x = xv.x + be0 + ea0 * ma0[0] + ea1 * ma0[1] + ea2 * ma0[2] + ea3 * ma0[3];
            o.y = xv.y + be1 + ea0 * ma1[0] + ea1 * ma1[1] + ea2 * ma1[2] + ea3 * ma1[3];
            *(float2*)&sXj[e * 130 + lane * 2] = o;
        }
        __syncthreads();

        // --- GEMM: ss(64x256) = rbf(64x128) @ Wd(128x256) ---
        f32x4 acc[4][4];
        #pragma unroll
        for (int m = 0; m < 4; ++m)
            #pragma unroll
            for (int i = 0; i < 4; ++i)
                acc[m][i] = (f32x4){0.f, 0.f, 0.f, 0.f};
        #pragma unroll
        for (int kk = 0; kk < 4; ++kk) {
            short8 af[4];
            #pragma unroll
            for (int m = 0; m < 4; ++m) {
                int row = m * 16 + l15;
                int byte = row * 256 + ((kk * 64 + l4 * 16) ^ ((row & 7) << 4));
                af[m] = *(const short8*)((const char*)sRbf + byte);
            }
            #pragma unroll
            for (int m = 0; m < 4; ++m)
                #pragma unroll
                for (int i = 0; i < 4; ++i)
                    acc[m][i] = __builtin_amdgcn_mfma_f32_16x16x32_bf16(
                        af[m], bfrag[kk][i], acc[m][i], 0, 0, 0);
        }

        // --- epilogue: msg = relu(xj*scale + shift); atomic scatter ---
        #pragma unroll
        for (int m = 0; m < 4; ++m) {
            #pragma unroll
            for (int p = 0; p < 2; ++p) {
                int h = (2 * w + p) * 16 + l15;
                #pragma unroll
                for (int r = 0; r < 4; ++r) {
                    int e = m * 16 + l4 * 4 + r;
                    float scale = acc[m][p][r] + bdS[p];
                    float shift = acc[m][2 + p][r] + bdH[p];
                    float xj = sXj[e * 130 + h];
                    float msg = fmaxf(fmaf(xj, scale, shift), 0.0f);
                    int dst = sDst[e];
                    if (dst >= 0)
                        atomicAdd(&agg[(size_t)dst * 128 + h], msg);
                }
            }
        }
    }
}

// ---------------------------------------------------------------------------
// Node kernel (persistent): out = relu((agg+x)@W1+b1)@W2+b2 (+prev, relu opt)
// 64 nodes/tile, 4 waves; wave w owns cols [32w, 32w+32) (nt = 2w, 2w+1).
// ---------------------------------------------------------------------------
__global__ void node_mfma_kernel(
    const float* __restrict__ agg, const float* __restrict__ x_dst,
    const short* __restrict__ pW1, const float* __restrict__ b1,
    const short* __restrict__ pW2, const float* __restrict__ b2,
    float* __restrict__ out, int N, int ntiles, int accumulate, int relu_out)
{
    __shared__ short sA[64 * 128];   // bf16 swizzled, 16 KB
    __shared__ short sH[64 * 128];   // bf16 swizzled, 16 KB

    const int t = threadIdx.x;
    const int lane = t & 63;
    const int w = t >> 6;
    const int l15 = lane & 15;
    const int l4 = lane >> 4;

    short8 w1f[4][2], w2f[4][2];
    #pragma unroll
    for (int kk = 0; kk < 4; ++kk)
        #pragma unroll
        for (int p = 0; p < 2; ++p) {
            int nt = 2 * w + p;
            w1f[kk][p] = *(const short8*)&pW1[((kk * 8 + nt) * 64 + lane) * 8];
            w2f[kk][p] = *(const short8*)&pW2[((kk * 8 + nt) * 64 + lane) * 8];
        }
    float b1v[2], b2v[2];
    #pragma unroll
    for (int p = 0; p < 2; ++p) {
        int col = (2 * w + p) * 16 + l15;
        b1v[p] = b1[col];
        b2v[p] = b2[col];
    }

    const float4* agg4 = (const float4*)agg;
    const float4* x4 = (const float4*)x_dst;

    for (int tile = blockIdx.x; tile < ntiles; tile += gridDim.x) {
        const int n0 = tile << 6;
        __syncthreads();
        // --- stage A = bf16(agg + x_dst) ---
        #pragma unroll
        for (int i = 0; i < 4; ++i) {
            int idx = i * 256 + t;          // 0..1023 = 64 rows x 16 chunks
            int row = idx >> 4, c8 = idx & 15;
            int gr = n0 + row; if (gr >= N) gr = N - 1;
            float4 a0 = agg4[(size_t)gr * 32 + c8 * 2];
            float4 a1 = agg4[(size_t)gr * 32 + c8 * 2 + 1];
            float4 x0 = x4[(size_t)gr * 32 + c8 * 2];
            float4 x1 = x4[(size_t)gr * 32 + c8 * 2 + 1];
            short8 v;
            v[0] = f2bs(a0.x + x0.x); v[1] = f2bs(a0.y + x0.y);
            v[2] = f2bs(a0.z + x0.z); v[3] = f2bs(a0.w + x0.w);
            v[4] = f2bs(a1.x + x1.x); v[5] = f2bs(a1.y + x1.y);
            v[6] = f2bs(a1.z + x1.z); v[7] = f2bs(a1.w + x1.w);
            int byte = row * 256 + ((c8 * 16) ^ ((row & 7) << 4));
            *(short8*)((char*)sA + byte) = v;
        }
        __syncthreads();

        // --- GEMM1: hidden = relu((agg+x)@W1 + b1) ---
        f32x4 acc[4][2];
        #pragma unroll
        for (int m = 0; m < 4; ++m) {
            acc[m][0] = (f32x4){0.f, 0.f, 0.f, 0.f};
            acc[m][1] = (f32x4){0.f, 0.f, 0.f, 0.f};
        }
        #pragma unroll
        for (int kk = 0; kk < 4; ++kk) {
            short8 af[4];
            #pragma unroll
            for (int m = 0; m < 4; ++m) {
                int row = m * 16 + l15;
                int byte = row * 256 + ((kk * 64 + l4 * 16) ^ ((row & 7) << 4));
                af[m] = *(const short8*)((const char*)sA + byte);
            }
            #pragma unroll
            for (int m = 0; m < 4; ++m)
                #pragma unroll
                for (int p = 0; p < 2; ++p)
                    acc[m][p] = __builtin_amdgcn_mfma_f32_16x16x32_bf16(
                        af[m], w1f[kk][p], acc[m][p], 0, 0, 0);
        }
        // hidden -> sH (bf16, swizzled)
        #pragma unroll
        for (int m = 0; m < 4; ++m)
            #pragma unroll
            for (int p = 0; p < 2; ++p) {
                int col = (2 * w + p) * 16 + l15;
                #pragma unroll
                for (int r = 0; r < 4; ++r) {
                    int row = m * 16 + l4 * 4 + r;
                    short hs = f2bs(fmaxf(acc[m][p][r] + b1v[p], 0.f));
                    int byte = row * 256 + ((col * 2) ^ ((row & 7) << 4));
                    *(short*)((char*)sH + byte) = hs;
                }
            }
        __syncthreads();

        // --- GEMM2: out = hidden@W2 + b2 ---
        f32x4 acc2[4][2];
        #pragma unroll
        for (int m = 0; m < 4; ++m) {
            acc2[m][0] = (f32x4){0.f, 0.f, 0.f, 0.f};
            acc2[m][1] = (f32x4){0.f, 0.f, 0.f, 0.f};
        }
        #pragma unroll
        for (int kk = 0; kk < 4; ++kk) {
            short8 af[4];
            #pragma unroll
            for (int m = 0; m < 4; ++m) {
                int row = m * 16 + l15;
                int byte = row * 256 + ((kk * 64 + l4 * 16) ^ ((row & 7) << 4));
                af[m] = *(const short8*)((const char*)sH + byte);
            }
            #pragma unroll
            for (int m = 0; m < 4; ++m)
                #pragma unroll
                for (int p = 0; p < 2; ++p)
                    acc2[m][p] = __builtin_amdgcn_mfma_f32_16x16x32_bf16(
                        af[m], w2f[kk][p], acc2[m][p], 0, 0, 0);
        }
        // --- epilogue ---
        #pragma unroll
        for (int m = 0; m < 4; ++m)
            #pragma unroll
            for (int p = 0; p < 2; ++p) {
                int col = (2 * w + p) * 16 + l15;
                #pragma unroll
                for (int r = 0; r < 4; ++r) {
                    int row = n0 + m * 16 + l4 * 4 + r;
                    if (row < N) {
                        float v = acc2[m][p][r] + b2v[p];
                        float* op = &out[(size_t)row * 128 + col];
                        if (accumulate) v += *op;
                        if (relu_out) v = fmaxf(v, 0.f);
                        *op = v;
                    }
                }
            }
    }
}

// ---------------------------------------------------------------------------
extern "C" void kernel_launch(void* const* d_in, const int* in_sizes, int n_in,
                              void* d_out, int out_size, void* d_ws, size_t ws_size,
                              hipStream_t stream)
{
    const float* x_lig   = (const float*)d_in[0];
    const float* x_pock  = (const float*)d_in[1];
    const int*   ei_bond = (const int*)d_in[2];
    const float* ew_bond = (const float*)d_in[3];
    const float* ea_bond = (const float*)d_in[4];
    const int*   ei_lp   = (const int*)d_in[5];
    const float* ew_lp   = (const float*)d_in[6];
    const float* ea_lp   = (const float*)d_in[7];
    const int*   ei_pl   = (const int*)d_in[8];
    const float* ew_pl   = (const float*)d_in[9];
    const float* ea_pl   = (const float*)d_in[10];
    const float* W0 = (const float*)d_in[11];
    const float* Wd = (const float*)d_in[12];
    const float* bd = (const float*)d_in[13];
    const float* We = (const float*)d_in[14];
    const float* be = (const float*)d_in[15];
    const float* W1 = (const float*)d_in[16];
    const float* b1 = (const float*)d_in[17];
    const float* W2 = (const float*)d_in[18];
    const float* b2 = (const float*)d_in[19];

    const int H = 128;
    const int N = in_sizes[0] / H;
    const int E_bond = in_sizes[3];
    const int E_lp   = in_sizes[6];
    const int E_pl   = in_sizes[9];

    // workspace layout
    float* agg  = (float*)d_ws;                       // N*128
    float* lig0 = agg + (size_t)N * H;                // N*128
    short* pWd  = (short*)(lig0 + (size_t)N * H);     // 6*32768
    short* pW1s = pWd + 6 * 32768;                    // 6*16384
    short* pW2s = pW1s + 6 * 16384;                   // 6*16384
    float* Mb   = (float*)(pW2s + 6 * 16384);         // 6*512

    float* outL  = (float*)d_out;           // lig output (layer 1)
    float* pock0 = outL + (size_t)N * H;    // layer-0 pock lives in outP slot
    float* outP  = pock0;

    pack_kernel<<<256, 256, 0, stream>>>(Wd, W1, W2, W0, We, pWd, pW1s, pW2s, Mb);

    const double start_d = exp(-5.0);
    const float rs    = (float)start_d;
    const float rstep = (float)((1.0 - start_d) / 127.0);
    const float rbeta = (float)std::pow(2.0 / 128.0 * (1.0 - start_d), -2.0);

    auto conv = [&](const float* xsrc, const float* xdst, const int* ei_,
                    const float* ew_, const float* ea_, int E, int l, int tt,
                    float* outbuf, int accum, int relu) {
        hipMemsetAsync(agg, 0, (size_t)N * H * sizeof(float), stream);
        const int lt = l * 3 + tt;
        const int ntE = (E + 63) / 64;
        const int gE = ntE < 768 ? ntE : 768;
        edge_mfma_kernel<<<gE, 256, 0, stream>>>(
            xsrc, ei_, ew_, ea_,
            pWd + (size_t)lt * 32768, bd + (size_t)lt * 256,
            Mb + (size_t)lt * 512, be + (size_t)lt * 128,
            agg, E, ntE, rs, rstep, rbeta);
        const int ntN = (N + 63) / 64;
        const int gN = ntN < 768 ? ntN : 768;
        node_mfma_kernel<<<gN, 256, 0, stream>>>(
            agg, xdst,
            pW1s + (size_t)lt * 16384, b1 + (size_t)lt * 128,
            pW2s + (size_t)lt * 16384, b2 + (size_t)lt * 128,
            outbuf, N, ntN, accum, relu);
    };

    // layer 0: lig = conv(bond) + conv(pl) [relu on sum]; pock = conv(lp) [relu]
    conv(x_lig,  x_lig,  ei_bond, ew_bond, ea_bond, E_bond, 0, 0, lig0,  0, 0);
    conv(x_pock, x_lig,  ei_pl,   ew_pl,   ea_pl,   E_pl,   0, 2, lig0,  1, 1);
    conv(x_lig,  x_pock, ei_lp,   ew_lp,   ea_lp,   E_lp,   0, 1, pock0, 0, 1);
    // layer 1: bond/pl read pock0 before lp overwrites it in-place
    conv(lig0,  lig0,  ei_bond, ew_bond, ea_bond, E_bond, 1, 0, outL, 0, 0);
    conv(pock0, lig0,  ei_pl,   ew_pl,   ea_pl,   E_pl,   1, 2, outL, 1, 0);
    conv(lig0,  pock0, ei_lp,   ew_lp,   ea_lp,   E_lp,   1, 1, outP, 0, 0);
}

// Round 3
// 1063.557 us; speedup vs baseline: 2.4058x; 2.1530x over previous
//
#include <hip/hip_runtime.h>
#include <hip/hip_bf16.h>
#include <hip/hip_fp16.h>
#include <cmath>

typedef __attribute__((ext_vector_type(8))) short short8_t;
typedef __attribute__((ext_vector_type(4))) float f32x4;

static __device__ __forceinline__ short f2bs(float f) {
    union { __hip_bfloat16 h; short s; } u;
    u.h = __float2bfloat16(f);
    return u.s;
}
static __device__ __forceinline__ float bs2f(unsigned int us) {
    union { float f; unsigned int i; } u;
    u.i = us << 16;
    return u.f;
}
static __device__ __forceinline__ unsigned int pack2bf(float a, float b) {
    return (unsigned int)(unsigned short)f2bs(a) |
           ((unsigned int)(unsigned short)f2bs(b) << 16);
}

// ---------------------------------------------------------------------------
// Pack kernel: Wd/W1/W2 -> bf16 MFMA B-fragment order; M = W0t @ We (fp32).
// ---------------------------------------------------------------------------
__global__ void pack_kernel(const float* __restrict__ Wd,
                            const float* __restrict__ W1,
                            const float* __restrict__ W2,
                            const float* __restrict__ W0,
                            const float* __restrict__ We,
                            short* __restrict__ pWd,
                            short* __restrict__ pW1,
                            short* __restrict__ pW2,
                            float* __restrict__ Mb)
{
    const int tid = blockIdx.x * blockDim.x + threadIdx.x;
    const int stride = gridDim.x * blockDim.x;
    for (int i = tid; i < 6 * 32768; i += stride) {
        int c = i >> 15, rem = i & 32767;
        int f = rem >> 9, l = (rem >> 3) & 63, j = rem & 7;
        int kk = f >> 4, nt = f & 15;
        int k = kk * 32 + (l >> 4) * 8 + j;
        int n = nt * 16 + (l & 15);
        pWd[i] = f2bs(Wd[(size_t)c * 32768 + k * 256 + n]);
    }
    for (int i = tid; i < 6 * 16384; i += stride) {
        int c = i >> 14, rem = i & 16383;
        int f = rem >> 9, l = (rem >> 3) & 63, j = rem & 7;
        int kk = f >> 3, nt = f & 7;
        int k = kk * 32 + (l >> 4) * 8 + j;
        int n = nt * 16 + (l & 15);
        pW1[i] = f2bs(W1[(size_t)c * 16384 + k * 128 + n]);
        pW2[i] = f2bs(W2[(size_t)c * 16384 + k * 128 + n]);
    }
    for (int i = tid; i < 6 * 512; i += stride) {
        int c = i >> 9, rem = i & 511;
        int a = rem >> 7, h = rem & 127;
        int t = c % 3;
        float m = 0.f;
        #pragma unroll
        for (int j = 0; j < 4; ++j)
            m = fmaf(W0[t * 16 + a * 4 + j], We[(size_t)c * 512 + j * 128 + h], m);
        Mb[i] = m;
    }
}

// ---------------------------------------------------------------------------
// Convert fp32 -> bf16 (two arrays)
// ---------------------------------------------------------------------------
__global__ void tobf16_kernel(const float* __restrict__ a, const float* __restrict__ b,
                              unsigned short* __restrict__ oa, unsigned short* __restrict__ ob,
                              int n4)
{
    int i = blockIdx.x * blockDim.x + threadIdx.x;
    const int stride = gridDim.x * blockDim.x;
    for (; i < n4; i += stride) {
        float4 va = ((const float4*)a)[i];
        uint2 pa; pa.x = pack2bf(va.x, va.y); pa.y = pack2bf(va.z, va.w);
        ((uint2*)oa)[i] = pa;
        float4 vb = ((const float4*)b)[i];
        uint2 pb; pb.x = pack2bf(vb.x, vb.y); pb.y = pack2bf(vb.z, vb.w);
        ((uint2*)ob)[i] = pb;
    }
}

// ---------------------------------------------------------------------------
// Edge kernel (persistent): 64 edges/tile, 256 threads (4 waves).
// bf16 x-gather, wave-local meta via shfl, fp16 packed atomics via LDS flush.
// LDS: sRbf 16KB (reused as msg fp16) + sXj 16KB = 32.8KB.
// ---------------------------------------------------------------------------
__global__ __launch_bounds__(256)
void edge_mfma_kernel(
    const unsigned short* __restrict__ xsb,   // bf16 x_src (N,128)
    const int* __restrict__ ei,
    const float* __restrict__ ew, const float* __restrict__ ea,
    const short* __restrict__ pWd, const float* __restrict__ bd,
    const float* __restrict__ Mb, const float* __restrict__ be,
    __half2* __restrict__ agg, int E, int ntiles,
    float rs, float rstep, float rbeta)
{
    __shared__ short sRbf[64 * 128];            // bf16 rbf, swizzled; reused as fp16 msg
    __shared__ unsigned short sXj[64 * 128];    // bf16 xj, swizzled

    const int t = threadIdx.x;
    const int lane = t & 63;
    const int w = t >> 6;
    const int l15 = lane & 15;
    const int l4 = lane >> 4;

    // --- per-block constants ---
    short8_t bfrag[4][4];   // [kk][0,1: scale nt / 2,3: shift nt]
    #pragma unroll
    for (int kk = 0; kk < 4; ++kk)
        #pragma unroll
        for (int i = 0; i < 4; ++i) {
            int nt = (i < 2) ? (2 * w + i) : (8 + 2 * w + (i - 2));
            bfrag[kk][i] = *(const short8_t*)&pWd[((kk * 16 + nt) * 64 + lane) * 8];
        }
    float bdS[2], bdH[2];
    #pragma unroll
    for (int p = 0; p < 2; ++p) {
        int h = (2 * w + p) * 16 + l15;
        bdS[p] = bd[h];
        bdH[p] = bd[128 + h];
    }
    const float be0 = be[2 * lane], be1 = be[2 * lane + 1];
    float ma0[4], ma1[4];
    #pragma unroll
    for (int a = 0; a < 4; ++a) {
        ma0[a] = Mb[a * 128 + 2 * lane];
        ma1[a] = Mb[a * 128 + 2 * lane + 1];
    }

    for (int tile = blockIdx.x; tile < ntiles; tile += gridDim.x) {
        const int e0 = tile << 6;

        // --- meta (no LDS, wave-local) + early gather issue ---
        int eL = e0 + lane;
        int eLc = eL < E ? eL : E - 1;
        float d = ew[eLc];
        float edv = __expf(-d);
        float dcc = fminf(d, 5.0f);
        float cutv = 0.5f * (__cosf(dcc * 0.62831853071795864769f) + 1.0f);
        int dstv = (eL < E) ? ei[E + eLc] : -1;
        int es = e0 + w * 16 + l15; if (es >= E) es = E - 1;
        int srcv = ei[es];
        float4 eav = *(const float4*)&ea[(size_t)es * 4];
        unsigned int gx[16];
        #pragma unroll
        for (int r = 0; r < 16; ++r) {
            int srn = __shfl(srcv, r);
            gx[r] = *(const unsigned int*)&xsb[(size_t)srn * 128 + lane * 2];
        }

        __syncthreads();   // B1: prev tile's flush/epilogue LDS reads done

        // --- rbf -> sRbf (wave w covers k in [32w,32w+32), edge = lane) ---
        {
            char* base = (char*)sRbf + lane * 256;
            #pragma unroll
            for (int c = 0; c < 4; ++c) {
                short8_t v;
                #pragma unroll
                for (int j = 0; j < 8; ++j) {
                    float mean = rs + (float)(w * 32 + c * 8 + j) * rstep;
                    float diff = edv - mean;
                    v[j] = f2bs(cutv * __expf(-rbeta * diff * diff));
                }
                *(short8_t*)(base + ((w * 64 + c * 16) ^ ((lane & 7) << 4))) = v;
            }
        }

        // --- xj = bf16(x) + ea@M + be -> sXj (wave w rows [16w,16w+16)) ---
        #pragma unroll
        for (int r = 0; r < 16; ++r) {
            float ea0 = __shfl(eav.x, r), ea1 = __shfl(eav.y, r);
            float ea2 = __shfl(eav.z, r), ea3 = __shfl(eav.w, r);
            unsigned int g = gx[r];
            float x0 = bs2f(g & 0xffffu), x1 = bs2f(g >> 16);
            float o0 = x0 + be0 + ea0 * ma0[0] + ea1 * ma0[1] + ea2 * ma0[2] + ea3 * ma0[3];
            float o1 = x1 + be1 + ea0 * ma1[0] + ea1 * ma1[1] + ea2 * ma1[2] + ea3 * ma1[3];
            int e = w * 16 + r;
            *(unsigned int*)((char*)sXj + e * 256 + ((lane * 4) ^ ((e & 7) << 4))) =
                pack2bf(o0, o1);
        }
        __syncthreads();   // B2

        // --- GEMM: ss(64x256) = rbf(64x128) @ Wd(128x256) ---
        f32x4 acc[4][4];
        #pragma unroll
        for (int m = 0; m < 4; ++m)
            #pragma unroll
            for (int i = 0; i < 4; ++i)
                acc[m][i] = (f32x4){0.f, 0.f, 0.f, 0.f};
        #pragma unroll
        for (int kk = 0; kk < 4; ++kk) {
            short8_t af[4];
            #pragma unroll
            for (int m = 0; m < 4; ++m) {
                int row = m * 16 + l15;
                int byte = row * 256 + ((kk * 64 + l4 * 16) ^ ((row & 7) << 4));
                af[m] = *(const short8_t*)((const char*)sRbf + byte);
            }
            #pragma unroll
            for (int m = 0; m < 4; ++m)
                #pragma unroll
                for (int i = 0; i < 4; ++i)
                    acc[m][i] = __builtin_amdgcn_mfma_f32_16x16x32_bf16(
                        af[m], bfrag[kk][i], acc[m][i], 0, 0, 0);
        }
        __syncthreads();   // B3: all MFMA reads of sRbf done

        // --- epilogue: msg = relu(xj*scale+shift) -> fp16 into sRbf region ---
        #pragma unroll
        for (int m = 0; m < 4; ++m) {
            #pragma unroll
            for (int p = 0; p < 2; ++p) {
                int h = (2 * w + p) * 16 + l15;
                #pragma unroll
                for (int r = 0; r < 4; ++r) {
                    int e = m * 16 + l4 * 4 + r;
                    float scale = acc[m][p][r] + bdS[p];
                    float shift = acc[m][2 + p][r] + bdH[p];
                    int off = e * 256 + ((h * 2) ^ ((e & 7) << 4));
                    float xj = bs2f((unsigned int)*(const unsigned short*)((const char*)sXj + off));
                    float msg = fmaxf(fmaf(xj, scale, shift), 0.0f);
                    *(__half*)((char*)sRbf + off) = __float2half(msg);
                }
            }
        }
        __syncthreads();   // B4

        // --- flush: coalesced packed-fp16 row atomics ---
        #pragma unroll
        for (int i = 0; i < 16; ++i) {
            int e = i * 4 + w;
            int dst = __shfl(dstv, e);
            unsigned int mr = *(const unsigned int*)
                ((const char*)sRbf + e * 256 + ((lane * 4) ^ ((e & 7) << 4)));
            if (dst >= 0) {
                __half2 hv = *(__half2*)&mr;
                unsafeAtomicAdd(agg + (size_t)dst * 64 + lane, hv);
            }
        }
    }
}

// ---------------------------------------------------------------------------
// Node kernel (persistent): out = relu((agg+x)@W1+b1)@W2+b2 (+prev, relu opt)
// agg fp16; x_dst fp32 OR bf16; out fp32 OR bf16.
// ---------------------------------------------------------------------------
__global__ __launch_bounds__(256)
void node_mfma_kernel(
    const __half2* __restrict__ agg,
    const float* __restrict__ xdf, const unsigned short* __restrict__ xdb,
    const short* __restrict__ pW1, const float* __restrict__ b1,
    const short* __restrict__ pW2, const float* __restrict__ b2,
    float* __restrict__ outf, unsigned short* __restrict__ outb,
    int N, int ntiles, int accumulate, int relu_out)
{
    __shared__ short sA[64 * 128];
    __shared__ short sH[64 * 128];

    const int t = threadIdx.x;
    const int lane = t & 63;
    const int w = t >> 6;
    const int l15 = lane & 15;
    const int l4 = lane >> 4;

    short8_t w1f[4][2], w2f[4][2];
    #pragma unroll
    for (int kk = 0; kk < 4; ++kk)
        #pragma unroll
        for (int p = 0; p < 2; ++p) {
            int nt = 2 * w + p;
            w1f[kk][p] = *(const short8_t*)&pW1[((kk * 8 + nt) * 64 + lane) * 8];
            w2f[kk][p] = *(const short8_t*)&pW2[((kk * 8 + nt) * 64 + lane) * 8];
        }
    float b1v[2], b2v[2];
    #pragma unroll
    for (int p = 0; p < 2; ++p) {
        int col = (2 * w + p) * 16 + l15;
        b1v[p] = b1[col];
        b2v[p] = b2[col];
    }

    for (int tile = blockIdx.x; tile < ntiles; tile += gridDim.x) {
        const int n0 = tile << 6;
        __syncthreads();
        // --- stage A = bf16(fp16 agg + x_dst) ---
        #pragma unroll
        for (int i = 0; i < 4; ++i) {
            int idx = i * 256 + t;          // 64 rows x 16 chunks of 8 cols
            int row = idx >> 4, c8 = idx & 15;
            int gr = n0 + row; if (gr >= N) gr = N - 1;
            union { float4 f; __half2 h[4]; } ar;
            ar.f = ((const float4*)agg)[(size_t)gr * 16 + c8];
            float xv[8];
            if (xdf) {
                float4 x0 = ((const float4*)xdf)[(size_t)gr * 32 + c8 * 2];
                float4 x1 = ((const float4*)xdf)[(size_t)gr * 32 + c8 * 2 + 1];
                xv[0] = x0.x; xv[1] = x0.y; xv[2] = x0.z; xv[3] = x0.w;
                xv[4] = x1.x; xv[5] = x1.y; xv[6] = x1.z; xv[7] = x1.w;
            } else {
                uint4 xr = ((const uint4*)xdb)[(size_t)gr * 16 + c8];
                xv[0] = bs2f(xr.x & 0xffffu); xv[1] = bs2f(xr.x >> 16);
                xv[2] = bs2f(xr.y & 0xffffu); xv[3] = bs2f(xr.y >> 16);
                xv[4] = bs2f(xr.z & 0xffffu); xv[5] = bs2f(xr.z >> 16);
                xv[6] = bs2f(xr.w & 0xffffu); xv[7] = bs2f(xr.w >> 16);
            }
            short8_t v;
            #pragma unroll
            for (int j = 0; j < 4; ++j) {
                float2 a2 = __half22float2(ar.h[j]);
                v[2 * j]     = f2bs(a2.x + xv[2 * j]);
                v[2 * j + 1] = f2bs(a2.y + xv[2 * j + 1]);
            }
            int byte = row * 256 + ((c8 * 16) ^ ((row & 7) << 4));
            *(short8_t*)((char*)sA + byte) = v;
        }
        __syncthreads();

        // --- GEMM1 ---
        f32x4 acc[4][2];
        #pragma unroll
        for (int m = 0; m < 4; ++m) {
            acc[m][0] = (f32x4){0.f, 0.f, 0.f, 0.f};
            acc[m][1] = (f32x4){0.f, 0.f, 0.f, 0.f};
        }
        #pragma unroll
        for (int kk = 0; kk < 4; ++kk) {
            short8_t af[4];
            #pragma unroll
            for (int m = 0; m < 4; ++m) {
                int row = m * 16 + l15;
                int byte = row * 256 + ((kk * 64 + l4 * 16) ^ ((row & 7) << 4));
                af[m] = *(const short8_t*)((const char*)sA + byte);
            }
            #pragma unroll
            for (int m = 0; m < 4; ++m)
                #pragma unroll
                for (int p = 0; p < 2; ++p)
                    acc[m][p] = __builtin_amdgcn_mfma_f32_16x16x32_bf16(
                        af[m], w1f[kk][p], acc[m][p], 0, 0, 0);
        }
        #pragma unroll
        for (int m = 0; m < 4; ++m)
            #pragma unroll
            for (int p = 0; p < 2; ++p) {
                int col = (2 * w + p) * 16 + l15;
                #pragma unroll
                for (int r = 0; r < 4; ++r) {
                    int row = m * 16 + l4 * 4 + r;
                    short hs = f2bs(fmaxf(acc[m][p][r] + b1v[p], 0.f));
                    int byte = row * 256 + ((col * 2) ^ ((row & 7) << 4));
                    *(short*)((char*)sH + byte) = hs;
                }
            }
        __syncthreads();

        // --- GEMM2 ---
        f32x4 acc2[4][2];
        #pragma unroll
        for (int m = 0; m < 4; ++m) {
            acc2[m][0] = (f32x4){0.f, 0.f, 0.f, 0.f};
            acc2[m][1] = (f32x4){0.f, 0.f, 0.f, 0.f};
        }
        #pragma unroll
        for (int kk = 0; kk < 4; ++kk) {
            short8_t af[4];
            #pragma unroll
            for (int m = 0; m < 4; ++m) {
                int row = m * 16 + l15;
                int byte = row * 256 + ((kk * 64 + l4 * 16) ^ ((row & 7) << 4));
                af[m] = *(const short8_t*)((const char*)sH + byte);
            }
            #pragma unroll
            for (int m = 0; m < 4; ++m)
                #pragma unroll
                for (int p = 0; p < 2; ++p)
                    acc2[m][p] = __builtin_amdgcn_mfma_f32_16x16x32_bf16(
                        af[m], w2f[kk][p], acc2[m][p], 0, 0, 0);
        }
        // --- epilogue ---
        #pragma unroll
        for (int m = 0; m < 4; ++m)
            #pragma unroll
            for (int p = 0; p < 2; ++p) {
                int col = (2 * w + p) * 16 + l15;
                #pragma unroll
                for (int r = 0; r < 4; ++r) {
                    int row = n0 + m * 16 + l4 * 4 + r;
                    if (row < N) {
                        float v = acc2[m][p][r] + b2v[p];
                        if (outf) {
                            float* op = &outf[(size_t)row * 128 + col];
                            if (accumulate) v += *op;
                            if (relu_out) v = fmaxf(v, 0.f);
                            *op = v;
                        } else {
                            unsigned short* op = &outb[(size_t)row * 128 + col];
                            if (accumulate) v += bs2f((unsigned int)*op);
                            if (relu_out) v = fmaxf(v, 0.f);
                            *op = (unsigned short)f2bs(v);
                        }
                    }
                }
            }
    }
}

// ---------------------------------------------------------------------------
extern "C" void kernel_launch(void* const* d_in, const int* in_sizes, int n_in,
                              void* d_out, int out_size, void* d_ws, size_t ws_size,
                              hipStream_t stream)
{
    const float* x_lig   = (const float*)d_in[0];
    const float* x_pock  = (const float*)d_in[1];
    const int*   ei_bond = (const int*)d_in[2];
    const float* ew_bond = (const float*)d_in[3];
    const float* ea_bond = (const float*)d_in[4];
    const int*   ei_lp   = (const int*)d_in[5];
    const float* ew_lp   = (const float*)d_in[6];
    const float* ea_lp   = (const float*)d_in[7];
    const int*   ei_pl   = (const int*)d_in[8];
    const float* ew_pl   = (const float*)d_in[9];
    const float* ea_pl   = (const float*)d_in[10];
    const float* W0 = (const float*)d_in[11];
    const float* Wd = (const float*)d_in[12];
    const float* bd = (const float*)d_in[13];
    const float* We = (const float*)d_in[14];
    const float* be = (const float*)d_in[15];
    const float* W1 = (const float*)d_in[16];
    const float* b1 = (const float*)d_in[17];
    const float* W2 = (const float*)d_in[18];
    const float* b2 = (const float*)d_in[19];

    const int H = 128;
    const int N = in_sizes[0] / H;
    const int E_bond = in_sizes[3];
    const int E_lp   = in_sizes[6];
    const int E_pl   = in_sizes[9];

    // workspace: A,B,C bf16 activations; agg fp16; packed weights
    unsigned short* A  = (unsigned short*)d_ws;           // x_lig_bf -> lig0_bf
    unsigned short* Bb = A  + (size_t)N * H;              // x_pock_bf
    unsigned short* C  = Bb + (size_t)N * H;              // pock0_bf
    __half* agg = (__half*)(C + (size_t)N * H);           // N*128 fp16
    short* pWd  = (short*)(agg + (size_t)N * H);
    short* pW1s = pWd + 6 * 32768;
    short* pW2s = pW1s + 6 * 16384;
    float* Mb   = (float*)(pW2s + 6 * 16384);

    float* outL = (float*)d_out;
    float* outP = outL + (size_t)N * H;

    tobf16_kernel<<<512, 256, 0, stream>>>(x_lig, x_pock, A, Bb, N * H / 4);
    pack_kernel<<<256, 256, 0, stream>>>(Wd, W1, W2, W0, We, pWd, pW1s, pW2s, Mb);

    const double start_d = exp(-5.0);
    const float rs    = (float)start_d;
    const float rstep = (float)((1.0 - start_d) / 127.0);
    const float rbeta = (float)std::pow(2.0 / 128.0 * (1.0 - start_d), -2.0);

    auto conv = [&](const unsigned short* src,
                    const float* xdf, const unsigned short* xdb,
                    const int* ei_, const float* ew_, const float* ea_, int E,
                    int l, int tt, float* outf, unsigned short* outb,
                    int accum, int relu) {
        hipMemsetAsync(agg, 0, (size_t)N * H * sizeof(__half), stream);
        const int lt = l * 3 + tt;
        const int ntE = (E + 63) / 64;
        const int gE = ntE < 1024 ? ntE : 1024;
        edge_mfma_kernel<<<gE, 256, 0, stream>>>(
            src, ei_, ew_, ea_,
            pWd + (size_t)lt * 32768, bd + (size_t)lt * 256,
            Mb + (size_t)lt * 512, be + (size_t)lt * 128,
            (__half2*)agg, E, ntE, rs, rstep, rbeta);
        const int ntN = (N + 63) / 64;
        const int gN = ntN < 1024 ? ntN : 1024;
        node_mfma_kernel<<<gN, 256, 0, stream>>>(
            (const __half2*)agg, xdf, xdb,
            pW1s + (size_t)lt * 16384, b1 + (size_t)lt * 128,
            pW2s + (size_t)lt * 16384, b2 + (size_t)lt * 128,
            outf, outb, N, ntN, accum, relu);
    };

    // layer 0 (order matters: A is overwritten by bond0's node after lp0+bond0 edges read it)
    conv(A,  x_pock, nullptr, ei_lp,   ew_lp,   ea_lp,   E_lp,   0, 1, nullptr, C, 0, 1);
    conv(A,  x_lig,  nullptr, ei_bond, ew_bond, ea_bond, E_bond, 0, 0, nullptr, A, 0, 0);
    conv(Bb, x_lig,  nullptr, ei_pl,   ew_pl,   ea_pl,   E_pl,   0, 2, nullptr, A, 1, 1);
    // layer 1: lig_bf = A, pock_bf = C
    conv(A, nullptr, A, ei_bond, ew_bond, ea_bond, E_bond, 1, 0, outL, nullptr, 0, 0);
    conv(C, nullptr, A, ei_pl,   ew_pl,   ea_pl,   E_pl,   1, 2, outL, nullptr, 1, 0);
    conv(A, nullptr, C, ei_lp,   ew_lp,   ea_lp,   E_lp,   1, 1, outP, nullptr, 0, 0);
}